// Round 5
// baseline (77.776 us; speedup 1.0000x reference)
//
#include <hip/hip_runtime.h>
#include <hip/hip_bf16.h>

// StackedPyrHourGlassLoss — HIP implementation, round 5 (resubmit of the
// round-3/4 design; two consecutive infra flakes, zero measurements so far).
// Single stage kernel (all 3 levels, blockIdx-range dispatch). Per-level
// (num,den) dice accumulators are fixed-point int64 global atomics
// (deterministic: integer adds are exact/commutative). Last-finishing block
// (device-scope counter) computes the final loss inline — no finalize kernel.
// A 64 B memset node zeroes the accumulators+counter each call.

constexpr int NBATCH = 2;
constexpr int EMB = 32;
constexpr int TGTC = 9;      // 1 gt + 8 affinity channels
constexpr int PZ = 5, PY = 15, PX = 15;
constexpr int P = PZ * PY * PX;   // 1125

constexpr int NBLK0 = NBATCH * 4 * 17 * 17;  // 2312
constexpr int NBLK1 = NBATCH * 4 * 9 * 9;    // 648
constexpr int NBLK2 = NBATCH * 4 * 9 * 9;    // 648
constexpr int NBLK_TOT = NBLK0 + NBLK1 + NBLK2;  // 3608

constexpr double FIX = 4294967296.0;   // 2^32 fixed-point scale

__device__ __forceinline__ unsigned long long to_fixed(float x)
{
    // x in [0, ~2250] -> fits in 64-bit at 2^32 scale with huge headroom
    return (unsigned long long)__double2ll_rn((double)x * FIX);
}

template <int D, int H, int W,
          int NB0, int NBH, int NBW,
          int SH, int SW,
          int DH, int DWIN,
          int OFFZ, int OFFY, int OFFX,
          int AFFB>
__device__ __forceinline__
void level_body(const int lbid,
                const float* __restrict__ pred,
                const int* __restrict__ tgt,
                const float* __restrict__ Wm,
                const float* __restrict__ bv,
                unsigned long long* __restrict__ accN,
                unsigned long long* __restrict__ accD)
{
    const int tid = threadIdx.x;

    int k  = lbid % NBW;
    int t1 = lbid / NBW;
    int j  = t1 % NBH;
    int t2 = t1 / NBH;
    int i  = t2 % NB0;
    int b  = t2 / NB0;

    const int HW = H * W;
    const int CH = D * HW;
    const int zc = OFFZ + i;           // z-stride is 1 at all levels
    const int yc = OFFY + j * SH;
    const int xc = OFFX + k * SW;
    const int cidx = zc * HW + yc * W + xc;

    __shared__ float s_emb[EMB];
    __shared__ int   s_c;
    __shared__ int   s_valid;

    if (tid == 0) {
        const int c = tgt[b * TGTC * CH + cidx];
        bool allaff = true;
        #pragma unroll
        for (int ch = 0; ch < 4; ++ch)
            allaff &= (tgt[(b * TGTC + AFFB + ch) * CH + cidx] != 0);
        s_c = c;
        s_valid = (c != 0) && allaff;
    }
    __syncthreads();

    if (!s_valid)
        return;                         // uniform exit; nothing to add

    if (tid < EMB)
        s_emb[tid] = pred[(b * EMB + tid) * CH + cidx];
    __syncthreads();

    const int* __restrict__ gtb = tgt + b * TGTC * CH;  // gt channel
    const int c = s_c;

    float num = 0.0f, den = 0.0f;
    for (int o = tid; o < P; o += 256) {
        const int pz = o / (PY * PX);
        const int r  = o - pz * (PY * PX);
        const int py = r / PX;
        const int px = r - py * PX;

        float dot = bv[o];
        #pragma unroll
        for (int e = 0; e < EMB; ++e)
            dot = fmaf(s_emb[e], Wm[e * P + o], dot);
        float pp = 1.0f / (1.0f + expf(-dot));

        const int zb = i + pz;
        const int yb = j * SH + py * DH;
        const int xb = k * SW + px * DWIN;
        bool anyz = false, anyd = false;
        #pragma unroll
        for (int wy = 0; wy < DH; ++wy) {
            #pragma unroll
            for (int wx = 0; wx < DWIN; ++wx) {
                const int g = gtb[zb * HW + (yb + wy) * W + (xb + wx)];
                anyz |= (g == 0);
                anyd |= (g != c);
            }
        }
        float trg = (anyz || !anyd) ? 0.0f : 1.0f;
        if (anyz) pp = 0.0f;

        num = fmaf(pp, trg, num);
        den += pp * pp + trg * trg;
    }

    #pragma unroll
    for (int off = 32; off > 0; off >>= 1) {
        num += __shfl_down(num, off);
        den += __shfl_down(den, off);
    }
    __shared__ float sn[4], sd[4];
    if ((tid & 63) == 0) { sn[tid >> 6] = num; sd[tid >> 6] = den; }
    __syncthreads();
    if (tid == 0) {
        const float N_ = sn[0] + sn[1] + sn[2] + sn[3];
        const float D_ = sd[0] + sd[1] + sd[2] + sd[3];
        atomicAdd(accN, to_fixed(N_));
        atomicAdd(accD, to_fixed(D_));
    }
}

__global__ __launch_bounds__(256)
void stage_kernel(const float* __restrict__ pred0, const int* __restrict__ tgt0,
                  const float* __restrict__ W0, const float* __restrict__ b0,
                  const float* __restrict__ pred1, const int* __restrict__ tgt1,
                  const float* __restrict__ W1, const float* __restrict__ b1,
                  const float* __restrict__ pred2, const int* __restrict__ tgt2,
                  const float* __restrict__ W2, const float* __restrict__ b2,
                  unsigned long long* __restrict__ acc,   // [6]: n0,d0,n1,d1,n2,d2
                  unsigned int* __restrict__ counter,
                  float* __restrict__ out)
{
    const int gb = blockIdx.x;
    if (gb < NBLK0) {
        // lvl0: 8,160,160  nb=(4,17,17) stride=6 dws=4 off=(2,30,30) aff 5..8
        level_body<8, 160, 160, 4, 17, 17, 6, 6, 4, 4, 2, 30, 30, 5>(
            gb, pred0, tgt0, W0, b0, acc + 0, acc + 1);
    } else if (gb < NBLK0 + NBLK1) {
        // lvl1: 8,80,80  nb=(4,9,9) stride=6 dws=2 off=(2,15,15) aff 1..4
        level_body<8, 80, 80, 4, 9, 9, 6, 6, 2, 2, 2, 15, 15, 1>(
            gb - NBLK0, pred1, tgt1, W1, b1, acc + 2, acc + 3);
    } else {
        // lvl2: 8,40,40  nb=(4,9,9) stride=3 dws=1 off=(2,7,7) aff 1..4
        level_body<8, 40, 40, 4, 9, 9, 3, 3, 1, 1, 2, 7, 7, 1>(
            gb - NBLK0 - NBLK1, pred2, tgt2, W2, b2, acc + 4, acc + 5);
    }

    // last-block-done finalize (no spinning: bounded work per block)
    if (threadIdx.x == 0) {
        __threadfence();                              // flush our atomics
        const unsigned int old = atomicAdd(counter, 1u);
        if (old == (unsigned int)(NBLK_TOT - 1)) {
            __threadfence();                          // acquire
            double loss = 0.0;
            #pragma unroll
            for (int l = 0; l < 3; ++l) {
                const long long n = (long long)__hip_atomic_load(
                    acc + 2 * l,     __ATOMIC_RELAXED, __HIP_MEMORY_SCOPE_AGENT);
                const long long d = (long long)__hip_atomic_load(
                    acc + 2 * l + 1, __ATOMIC_RELAXED, __HIP_MEMORY_SCOPE_AGENT);
                const double nd = (double)n / FIX;
                const double dd = (double)d / FIX;
                loss += -2.0 * nd / fmax(dd, 1e-6);
            }
            out[0] = (float)loss;
        }
    }
}

extern "C" void kernel_launch(void* const* d_in, const int* in_sizes, int n_in,
                              void* d_out, int out_size, void* d_ws, size_t ws_size,
                              hipStream_t stream)
{
    const float* pred0 = (const float*)d_in[0];
    const int*   tgt0  = (const int*)  d_in[1];
    const float* W0    = (const float*)d_in[2];
    const float* b0    = (const float*)d_in[3];
    const float* pred1 = (const float*)d_in[4];
    const int*   tgt1  = (const int*)  d_in[5];
    const float* W1    = (const float*)d_in[6];
    const float* b1    = (const float*)d_in[7];
    const float* pred2 = (const float*)d_in[8];
    const int*   tgt2  = (const int*)  d_in[9];
    const float* W2    = (const float*)d_in[10];
    const float* b2    = (const float*)d_in[11];

    float* out = (float*)d_out;
    unsigned long long* acc = (unsigned long long*)d_ws;     // 6 x int64
    unsigned int* counter   = (unsigned int*)(acc + 6);

    hipMemsetAsync(d_ws, 0, 64, stream);   // zero accs + counter each call

    stage_kernel<<<NBLK_TOT, 256, 0, stream>>>(
        pred0, tgt0, W0, b0, pred1, tgt1, W1, b1, pred2, tgt2, W2, b2,
        acc, counter, out);
}

// Round 6
// 19.913 us; speedup vs baseline: 3.9058x; 3.9058x over previous
//
#include <hip/hip_runtime.h>
#include <hip/hip_bf16.h>

// StackedPyrHourGlassLoss — round 6.
// REVERT to the measured-best 2-node structure (round 2, 20.5 µs):
//   stage (3608 blocks, per-block float2 partial, no atomics/fences)
//   -> finalize (1 block).
// Round-5 lesson: per-block __threadfence + same-address atomic chain cost
// ~25 ns x gridDim serialized (77.8 µs total) — never again at this scale.
// Trims vs round 2: fast sigmoid (v_exp + v_rcp), single-pass finalize.

constexpr int NBATCH = 2;
constexpr int EMB = 32;
constexpr int TGTC = 9;      // 1 gt + 8 affinity channels
constexpr int PZ = 5, PY = 15, PX = 15;
constexpr int P = PZ * PY * PX;   // 1125

constexpr int NBLK0 = NBATCH * 4 * 17 * 17;  // 2312
constexpr int NBLK1 = NBATCH * 4 * 9 * 9;    // 648
constexpr int NBLK2 = NBATCH * 4 * 9 * 9;    // 648
constexpr int NBLK_TOT = NBLK0 + NBLK1 + NBLK2;  // 3608

template <int D, int H, int W,
          int NB0, int NBH, int NBW,
          int SH, int SW,
          int DH, int DWIN,
          int OFFZ, int OFFY, int OFFX,
          int AFFB>
__device__ __forceinline__
void level_body(const int lbid,
                const float* __restrict__ pred,
                const int* __restrict__ tgt,
                const float* __restrict__ Wm,
                const float* __restrict__ bv,
                float* __restrict__ partials)
{
    const int tid = threadIdx.x;

    int k  = lbid % NBW;
    int t1 = lbid / NBW;
    int j  = t1 % NBH;
    int t2 = t1 / NBH;
    int i  = t2 % NB0;
    int b  = t2 / NB0;

    const int HW = H * W;
    const int CH = D * HW;
    const int zc = OFFZ + i;           // z-stride is 1 at all levels
    const int yc = OFFY + j * SH;
    const int xc = OFFX + k * SW;
    const int cidx = zc * HW + yc * W + xc;

    __shared__ float s_emb[EMB];
    __shared__ int   s_c;
    __shared__ int   s_valid;

    if (tid == 0) {
        const int c = tgt[b * TGTC * CH + cidx];
        bool allaff = true;
        #pragma unroll
        for (int ch = 0; ch < 4; ++ch)
            allaff &= (tgt[(b * TGTC + AFFB + ch) * CH + cidx] != 0);
        s_c = c;
        s_valid = (c != 0) && allaff;
    }
    __syncthreads();

    if (!s_valid) {
        if (tid == 0) {
            partials[2 * lbid]     = 0.0f;
            partials[2 * lbid + 1] = 0.0f;
        }
        return;
    }

    if (tid < EMB)
        s_emb[tid] = pred[(b * EMB + tid) * CH + cidx];
    __syncthreads();

    const int* __restrict__ gtb = tgt + b * TGTC * CH;  // gt channel
    const int c = s_c;

    float num = 0.0f, den = 0.0f;
    for (int o = tid; o < P; o += 256) {
        const int pz = o / (PY * PX);
        const int r  = o - pz * (PY * PX);
        const int py = r / PX;
        const int px = r - py * PX;

        float dot = bv[o];
        #pragma unroll
        for (int e = 0; e < EMB; ++e)
            dot = fmaf(s_emb[e], Wm[e * P + o], dot);
        // fast sigmoid: v_exp + v_rcp (error ~1e-7 rel, threshold is 4.7e-2)
        float pp = __builtin_amdgcn_rcpf(1.0f + __expf(-dot));

        const int zb = i + pz;
        const int yb = j * SH + py * DH;
        const int xb = k * SW + px * DWIN;
        bool anyz = false, anyd = false;
        #pragma unroll
        for (int wy = 0; wy < DH; ++wy) {
            #pragma unroll
            for (int wx = 0; wx < DWIN; ++wx) {
                const int g = gtb[zb * HW + (yb + wy) * W + (xb + wx)];
                anyz |= (g == 0);
                anyd |= (g != c);
            }
        }
        float trg = (anyz || !anyd) ? 0.0f : 1.0f;
        if (anyz) pp = 0.0f;

        num = fmaf(pp, trg, num);
        den += pp * pp + trg * trg;
    }

    #pragma unroll
    for (int off = 32; off > 0; off >>= 1) {
        num += __shfl_down(num, off);
        den += __shfl_down(den, off);
    }
    __shared__ float sn[4], sd[4];
    if ((tid & 63) == 0) { sn[tid >> 6] = num; sd[tid >> 6] = den; }
    __syncthreads();
    if (tid == 0) {
        partials[2 * lbid]     = sn[0] + sn[1] + sn[2] + sn[3];
        partials[2 * lbid + 1] = sd[0] + sd[1] + sd[2] + sd[3];
    }
}

__global__ __launch_bounds__(256)
void stage_kernel(const float* __restrict__ pred0, const int* __restrict__ tgt0,
                  const float* __restrict__ W0, const float* __restrict__ b0,
                  const float* __restrict__ pred1, const int* __restrict__ tgt1,
                  const float* __restrict__ W1, const float* __restrict__ b1,
                  const float* __restrict__ pred2, const int* __restrict__ tgt2,
                  const float* __restrict__ W2, const float* __restrict__ b2,
                  float* __restrict__ partials)
{
    const int gb = blockIdx.x;
    if (gb < NBLK0) {
        // lvl0: 8,160,160  nb=(4,17,17) stride=6 dws=4 off=(2,30,30) aff 5..8
        level_body<8, 160, 160, 4, 17, 17, 6, 6, 4, 4, 2, 30, 30, 5>(
            gb, pred0, tgt0, W0, b0, partials);
    } else if (gb < NBLK0 + NBLK1) {
        // lvl1: 8,80,80  nb=(4,9,9) stride=6 dws=2 off=(2,15,15) aff 1..4
        level_body<8, 80, 80, 4, 9, 9, 6, 6, 2, 2, 2, 15, 15, 1>(
            gb - NBLK0, pred1, tgt1, W1, b1, partials + 2 * NBLK0);
    } else {
        // lvl2: 8,40,40  nb=(4,9,9) stride=3 dws=1 off=(2,7,7) aff 1..4
        level_body<8, 40, 40, 4, 9, 9, 3, 3, 1, 1, 2, 7, 7, 1>(
            gb - NBLK0 - NBLK1, pred2, tgt2, W2, b2,
            partials + 2 * (NBLK0 + NBLK1));
    }
}

__global__ __launch_bounds__(256)
void finalize_kernel(const float* __restrict__ partials, float* __restrict__ out)
{
    const int tid = threadIdx.x;

    // single pass over all 3608 (num,den) pairs; classify by level range
    float n0 = 0.f, d0 = 0.f, n1 = 0.f, d1 = 0.f, n2 = 0.f, d2 = 0.f;
    const float2* p2 = (const float2*)partials;
    #pragma unroll 4
    for (int p = tid; p < NBLK_TOT; p += 256) {
        const float2 v = p2[p];
        if (p < NBLK0)              { n0 += v.x; d0 += v.y; }
        else if (p < NBLK0 + NBLK1) { n1 += v.x; d1 += v.y; }
        else                        { n2 += v.x; d2 += v.y; }
    }

    #pragma unroll
    for (int off = 32; off > 0; off >>= 1) {
        n0 += __shfl_down(n0, off);  d0 += __shfl_down(d0, off);
        n1 += __shfl_down(n1, off);  d1 += __shfl_down(d1, off);
        n2 += __shfl_down(n2, off);  d2 += __shfl_down(d2, off);
    }
    __shared__ float s[4][6];
    if ((tid & 63) == 0) {
        const int w = tid >> 6;
        s[w][0] = n0; s[w][1] = d0; s[w][2] = n1;
        s[w][3] = d1; s[w][4] = n2; s[w][5] = d2;
    }
    __syncthreads();
    if (tid == 0) {
        float acc[6];
        #pragma unroll
        for (int q = 0; q < 6; ++q)
            acc[q] = s[0][q] + s[1][q] + s[2][q] + s[3][q];
        float loss = 0.0f;
        loss += -2.0f * acc[0] / fmaxf(acc[1], 1e-6f);
        loss += -2.0f * acc[2] / fmaxf(acc[3], 1e-6f);
        loss += -2.0f * acc[4] / fmaxf(acc[5], 1e-6f);
        out[0] = loss;
    }
}

extern "C" void kernel_launch(void* const* d_in, const int* in_sizes, int n_in,
                              void* d_out, int out_size, void* d_ws, size_t ws_size,
                              hipStream_t stream)
{
    const float* pred0 = (const float*)d_in[0];
    const int*   tgt0  = (const int*)  d_in[1];
    const float* W0    = (const float*)d_in[2];
    const float* b0    = (const float*)d_in[3];
    const float* pred1 = (const float*)d_in[4];
    const int*   tgt1  = (const int*)  d_in[5];
    const float* W1    = (const float*)d_in[6];
    const float* b1    = (const float*)d_in[7];
    const float* pred2 = (const float*)d_in[8];
    const int*   tgt2  = (const int*)  d_in[9];
    const float* W2    = (const float*)d_in[10];
    const float* b2    = (const float*)d_in[11];

    float* out      = (float*)d_out;
    float* partials = (float*)d_ws;   // 3608 (num,den) pairs

    stage_kernel<<<NBLK_TOT, 256, 0, stream>>>(
        pred0, tgt0, W0, b0, pred1, tgt1, W1, b1, pred2, tgt2, W2, b2,
        partials);
    finalize_kernel<<<1, 256, 0, stream>>>(partials, out);
}